// Round 1
// baseline (284.276 us; speedup 1.0000x reference)
//
#include <hip/hip_runtime.h>

#define NHEAD 4
#define CDIM 32
#define HC 128
#define NGRAPH 8
#define NPER 2048
#define NN 16384
#define EE 1048576
#define RSQRT_C 0.17677669529663687f  // 1/sqrt(32)

__device__ __forceinline__ float sigmoidf_(float v){ return 1.0f/(1.0f + __expf(-v)); }

// ---------------- zero deg ----------------
__global__ void k_zero(unsigned* __restrict__ deg){
  int t = blockIdx.x*256 + threadIdx.x;
  deg[t] = 0u;
}

// ---------------- per-node precompute: A[n,h,j], qWe[n,h], b0[n,h] ----------------
// q[n,h,c] = bq[hc] + sum_i x[n,i] Wq[i*128+hc]
// A[n,h,j]  = RS * sum_c q * Wk[j*128+hc]
// qWe[n,h]  = RS * sum_c q * We[hc]
// b0[n,h]   = RS * sum_c q * (bk[hc]+be[hc])
__global__ void k_pre(const float* __restrict__ x,
                      const float* __restrict__ Wq, const float* __restrict__ bq,
                      const float* __restrict__ Wk, const float* __restrict__ bk,
                      const float* __restrict__ be, const float* __restrict__ We,
                      float* __restrict__ A, float* __restrict__ qWe, float* __restrict__ b0){
  int tid = blockIdx.x*256 + threadIdx.x;   // n*4 + h
  int n = tid >> 2, h = tid & 3;
  const float4 xn = *(const float4*)&x[n*4];
  float a0=0.f,a1=0.f,a2=0.f,a3=0.f,qw=0.f,bb=0.f;
#pragma unroll
  for (int c=0;c<32;c++){
    int hc = h*32 + c;
    float q = bq[hc] + xn.x*Wq[hc] + xn.y*Wq[128+hc] + xn.z*Wq[256+hc] + xn.w*Wq[384+hc];
    a0 += q*Wk[hc];     a1 += q*Wk[128+hc];
    a2 += q*Wk[256+hc]; a3 += q*Wk[384+hc];
    qw += q*We[hc];
    bb += q*(bk[hc] + be[hc]);
  }
  A[tid*4+0]=a0*RSQRT_C; A[tid*4+1]=a1*RSQRT_C; A[tid*4+2]=a2*RSQRT_C; A[tid*4+3]=a3*RSQRT_C;
  qWe[tid]=qw*RSQRT_C; b0[tid]=bb*RSQRT_C;
}

// ---------------- CSR build ----------------
__global__ void k_hist(const int* __restrict__ ei, unsigned* __restrict__ deg){
  int e = blockIdx.x*256 + threadIdx.x;
  atomicAdd(&deg[ei[EE + e]], 1u);
}

__global__ __launch_bounds__(1024) void k_scan(const unsigned* __restrict__ deg,
                                               unsigned* __restrict__ rowptr,
                                               unsigned* __restrict__ cursor){
  __shared__ unsigned tmp[1024];
  int t = threadIdx.x;
  int base = t*16;
  unsigned loc[16]; unsigned s=0;
#pragma unroll
  for (int i=0;i<16;i++){ loc[i]=s; s += deg[base+i]; }
  tmp[t]=s; __syncthreads();
  for (int off=1; off<1024; off<<=1){
    unsigned v = (t>=off)? tmp[t-off] : 0u;
    __syncthreads();
    tmp[t] += v;
    __syncthreads();
  }
  unsigned boff = (t>0)? tmp[t-1] : 0u;
#pragma unroll
  for (int i=0;i<16;i++){ unsigned r = boff + loc[i]; rowptr[base+i]=r; cursor[base+i]=r; }
  if (t==1023) rowptr[NN] = tmp[1023];
}

__global__ void k_scatter(const int* __restrict__ ei, const float* __restrict__ ea,
                          unsigned* __restrict__ cursor,
                          int* __restrict__ csr_src, float* __restrict__ csr_attr){
  int e = blockIdx.x*256 + threadIdx.x;
  int d = ei[EE + e];
  unsigned pos = atomicAdd(&cursor[d], 1u);
  csr_src[pos]  = ei[e];
  csr_attr[pos] = ea[e];
}

// ---------------- fused attention + beta gate + Linear/ReLU ----------------
// one wave per node
__global__ __launch_bounds__(256) void k_attn(
    const float* __restrict__ x,
    const float* __restrict__ A, const float* __restrict__ qWe, const float* __restrict__ b0,
    const unsigned* __restrict__ rowptr,
    const int* __restrict__ csr_src, const float* __restrict__ csr_attr,
    const float* __restrict__ Wv, const float* __restrict__ bv,
    const float* __restrict__ We, const float* __restrict__ be,
    const float* __restrict__ Ws, const float* __restrict__ bs,
    const float* __restrict__ Wb,
    const float* __restrict__ Wl, const float* __restrict__ bl,
    float* __restrict__ hout){
  const int lane = threadIdx.x & 63;
  const int wid  = threadIdx.x >> 6;
  int n = (blockIdx.x << 2) + wid;
  n = __builtin_amdgcn_readfirstlane(n);

  float Ah[4][4], qW[4], bh[4];
#pragma unroll
  for (int h=0;h<4;h++){
    qW[h] = qWe[n*4+h];
    bh[h] = b0[n*4+h];
#pragma unroll
    for (int j=0;j<4;j++) Ah[h][j] = A[(n*4+h)*4+j];
  }
  const unsigned beg = rowptr[n], end = rowptr[n+1];
  const int deg = (int)(end - beg);

  float m[4], sw[4], sa[4], sx[4][4];
#pragma unroll
  for (int h=0;h<4;h++){ m[h]=-3.0e38f; sw[h]=0.f; sa[h]=0.f;
#pragma unroll
    for (int j=0;j<4;j++) sx[h][j]=0.f; }

  for (unsigned i = beg + lane; i < end; i += 64){
    const int s = csr_src[i];
    const float at = csr_attr[i];
    const float4 xs = *(const float4*)&x[s*4];
#pragma unroll
    for (int h=0;h<4;h++){
      float al = bh[h] + at*qW[h] + Ah[h][0]*xs.x + Ah[h][1]*xs.y + Ah[h][2]*xs.z + Ah[h][3]*xs.w;
      float mn = fmaxf(m[h], al);
      float so = __expf(m[h]-mn);
      float w  = __expf(al-mn);
      sw[h] = sw[h]*so + w;
      sa[h] = sa[h]*so + w*at;
      sx[h][0] = sx[h][0]*so + w*xs.x;
      sx[h][1] = sx[h][1]*so + w*xs.y;
      sx[h][2] = sx[h][2]*so + w*xs.z;
      sx[h][3] = sx[h][3]*so + w*xs.w;
      m[h] = mn;
    }
  }

  // butterfly merge of (m, sums) across 64 lanes
#pragma unroll
  for (int off=1; off<64; off<<=1){
#pragma unroll
    for (int h=0;h<4;h++){
      float mo  = __shfl_xor(m[h],  off, 64);
      float swo = __shfl_xor(sw[h], off, 64);
      float sao = __shfl_xor(sa[h], off, 64);
      float s0  = __shfl_xor(sx[h][0], off, 64);
      float s1  = __shfl_xor(sx[h][1], off, 64);
      float s2  = __shfl_xor(sx[h][2], off, 64);
      float s3  = __shfl_xor(sx[h][3], off, 64);
      float mn = fmaxf(m[h], mo);
      float fa = __expf(m[h]-mn);
      float fb = __expf(mo-mn);
      sw[h] = sw[h]*fa + swo*fb;
      sa[h] = sa[h]*fa + sao*fb;
      sx[h][0]=sx[h][0]*fa + s0*fb;
      sx[h][1]=sx[h][1]*fa + s1*fb;
      sx[h][2]=sx[h][2]*fa + s2*fb;
      sx[h][3]=sx[h][3]*fa + s3*fb;
      m[h]=mn;
    }
  }

  // each lane produces 2 of the 128 concat-channels
  const int hc0 = lane*2, hc1 = hc0+1;
  const int h0 = hc0 >> 5, h1 = hc1 >> 5;
  float ov0 = 0.f, ov1 = 0.f;
  if (deg > 0){
    ov0 = (sx[h0][0]*Wv[hc0] + sx[h0][1]*Wv[128+hc0] + sx[h0][2]*Wv[256+hc0] + sx[h0][3]*Wv[384+hc0]
           + sa[h0]*We[hc0]) / sw[h0] + bv[hc0] + be[hc0];
    ov1 = (sx[h1][0]*Wv[hc1] + sx[h1][1]*Wv[128+hc1] + sx[h1][2]*Wv[256+hc1] + sx[h1][3]*Wv[384+hc1]
           + sa[h1]*We[hc1]) / sw[h1] + bv[hc1] + be[hc1];
  }
  const float4 xn = *(const float4*)&x[n*4];
  float xr0 = bs[hc0] + xn.x*Ws[hc0] + xn.y*Ws[128+hc0] + xn.z*Ws[256+hc0] + xn.w*Ws[384+hc0];
  float xr1 = bs[hc1] + xn.x*Ws[hc1] + xn.y*Ws[128+hc1] + xn.z*Ws[256+hc1] + xn.w*Ws[384+hc1];

  float part = ov0*Wb[hc0] + xr0*Wb[128+hc0] + (ov0-xr0)*Wb[256+hc0]
             + ov1*Wb[hc1] + xr1*Wb[128+hc1] + (ov1-xr1)*Wb[256+hc1];
#pragma unroll
  for (int off=1; off<64; off<<=1) part += __shfl_xor(part, off, 64);
  const float beta = sigmoidf_(part);
  const float o0 = beta*xr0 + (1.f-beta)*ov0;
  const float o1 = beta*xr1 + (1.f-beta)*ov1;

  __shared__ float lout[4][130];
  lout[wid][hc0] = o0;
  lout[wid][hc1] = o1;
  __syncthreads();

  const int c = lane & 31, half = lane >> 5;
  float acc = 0.f;
#pragma unroll 8
  for (int q2=0; q2<64; q2++){
    int hc = half*64 + q2;
    acc += lout[wid][hc] * Wl[hc*32 + c];
  }
  acc += __shfl_xor(acc, 32, 64);
  if (lane < 32) hout[n*32 + c] = fmaxf(acc + bl[c], 0.f);
}

// ---------------- GraphNorm stats (deterministic, per-graph blocks) ----------------
__global__ __launch_bounds__(1024) void k_stats1(const float* __restrict__ h, float* __restrict__ mean){
  int b = blockIdx.x;
  int t = threadIdx.x; int c = t & 31, g = t >> 5;
  float s = 0.f;
  for (int r=g; r<NPER; r+=32) s += h[(b*NPER+r)*32 + c];
  __shared__ float tmp[1024];
  tmp[t]=s; __syncthreads();
  for (int off=512; off>=32; off>>=1){ if (t<off) tmp[t]+=tmp[t+off]; __syncthreads(); }
  if (t<32) mean[b*32+t] = tmp[t] * (1.0f/NPER);
}

__global__ __launch_bounds__(1024) void k_stats2(const float* __restrict__ h, const float* __restrict__ mean,
                                                 const float* __restrict__ gms, const float* __restrict__ gw,
                                                 float* __restrict__ scv){
  int b = blockIdx.x;
  int t = threadIdx.x; int c = t & 31, g = t >> 5;
  float mu = mean[b*32+c]; float ms = gms[c];
  float s = 0.f;
  for (int r=g; r<NPER; r+=32){ float v = h[(b*NPER+r)*32 + c] - ms*mu; s += v*v; }
  __shared__ float tmp[1024];
  tmp[t]=s; __syncthreads();
  for (int off=512; off>=32; off>>=1){ if (t<off) tmp[t]+=tmp[t+off]; __syncthreads(); }
  if (t<32) scv[b*32+t] = gw[t] * rsqrtf(tmp[t]*(1.0f/NPER) + 1e-5f);
}

__global__ void k_norm(const float* __restrict__ h, const float* __restrict__ mean,
                       const float* __restrict__ scv, const float* __restrict__ gms,
                       const float* __restrict__ gb, float* __restrict__ Z){
  int idx = blockIdx.x*256 + threadIdx.x;
  int c = idx & 31; int n = idx >> 5; int b = n >> 11;
  Z[idx] = (h[idx] - gms[c]*mean[b*32+c]) * scv[b*32+c] + gb[c];
}

// ---------------- decoder: adj = sigmoid(Z Z^T) per graph ----------------
__global__ __launch_bounds__(256) void k_gemm(const float* __restrict__ Z, float* __restrict__ out){
  __shared__ float tA[32][68];
  __shared__ float tB[32][68];
  const int t = threadIdx.x;
  const int bx = blockIdx.x, by = blockIdx.y, bz = blockIdx.z;
  const float* Zb = Z + (size_t)bz * NPER * 32;
  {
    const int r  = t >> 2;
    const int c0 = (t & 3) * 8;
    const float* pa = Zb + (by*64 + r)*32 + c0;
    const float* pb = Zb + (bx*64 + r)*32 + c0;
    float4 a0 = *(const float4*)pa;
    float4 a1 = *(const float4*)(pa + 4);
    float4 q0 = *(const float4*)pb;
    float4 q1 = *(const float4*)(pb + 4);
    tA[c0+0][r]=a0.x; tA[c0+1][r]=a0.y; tA[c0+2][r]=a0.z; tA[c0+3][r]=a0.w;
    tA[c0+4][r]=a1.x; tA[c0+5][r]=a1.y; tA[c0+6][r]=a1.z; tA[c0+7][r]=a1.w;
    tB[c0+0][r]=q0.x; tB[c0+1][r]=q0.y; tB[c0+2][r]=q0.z; tB[c0+3][r]=q0.w;
    tB[c0+4][r]=q1.x; tB[c0+5][r]=q1.y; tB[c0+6][r]=q1.z; tB[c0+7][r]=q1.w;
  }
  __syncthreads();
  const int tx = t & 15, ty = t >> 4;
  float acc[4][4] = {{0.f}};
#pragma unroll
  for (int k=0;k<32;k++){
    const float4 av = *(const float4*)&tA[k][ty*4];
    const float4 bv = *(const float4*)&tB[k][tx*4];
    const float a4[4] = {av.x, av.y, av.z, av.w};
    const float b4[4] = {bv.x, bv.y, bv.z, bv.w};
#pragma unroll
    for (int i=0;i<4;i++)
#pragma unroll
      for (int j=0;j<4;j++) acc[i][j] += a4[i]*b4[j];
  }
  float* op = out + (size_t)bz*NPER*NPER + (size_t)(by*64 + ty*4)*NPER + (bx*64 + tx*4);
#pragma unroll
  for (int i=0;i<4;i++){
    float4 o;
    o.x = sigmoidf_(acc[i][0]); o.y = sigmoidf_(acc[i][1]);
    o.z = sigmoidf_(acc[i][2]); o.w = sigmoidf_(acc[i][3]);
    *(float4*)(op + (size_t)i*NPER) = o;
  }
}

extern "C" void kernel_launch(void* const* d_in, const int* in_sizes, int n_in,
                              void* d_out, int out_size, void* d_ws, size_t ws_size,
                              hipStream_t stream){
  const float* x  = (const float*)d_in[0];
  const int*   ei = (const int*)d_in[1];
  const float* ea = (const float*)d_in[2];
  // d_in[3] batch_index: layout is b = n >> 11 per the reference reshape
  const float* Wq = (const float*)d_in[4];
  const float* bq = (const float*)d_in[5];
  const float* Wk = (const float*)d_in[6];
  const float* bk = (const float*)d_in[7];
  const float* Wv = (const float*)d_in[8];
  const float* bv = (const float*)d_in[9];
  const float* We = (const float*)d_in[10];
  const float* be = (const float*)d_in[11];
  const float* Ws = (const float*)d_in[12];
  const float* bs = (const float*)d_in[13];
  const float* Wb = (const float*)d_in[14];
  const float* Wl = (const float*)d_in[15];
  const float* bl = (const float*)d_in[16];
  const float* gw = (const float*)d_in[17];
  const float* gb = (const float*)d_in[18];
  const float* gms= (const float*)d_in[19];
  float* out = (float*)d_out;

  char* p = (char*)d_ws;
  auto bump = [&](size_t bytes)->char*{ char* r = p; p += (bytes + 255) & ~(size_t)255; return r; };
  float*    Aw     = (float*)bump((size_t)NN*16*4);
  float*    qWe    = (float*)bump((size_t)NN*4*4);
  float*    b0     = (float*)bump((size_t)NN*4*4);
  unsigned* deg    = (unsigned*)bump((size_t)NN*4);
  unsigned* rowptr = (unsigned*)bump((size_t)(NN+1)*4);
  unsigned* cursor = (unsigned*)bump((size_t)NN*4);
  int*      csr_src  = (int*)bump((size_t)EE*4);
  float*    csr_attr = (float*)bump((size_t)EE*4);
  float*    hbuf   = (float*)bump((size_t)NN*32*4);
  float*    mean   = (float*)bump((size_t)NGRAPH*32*4);
  float*    scv    = (float*)bump((size_t)NGRAPH*32*4);
  float*    Zbuf   = (float*)bump((size_t)NN*32*4);

  hipLaunchKernelGGL(k_zero, dim3(NN/256), dim3(256), 0, stream, deg);
  hipLaunchKernelGGL(k_pre,  dim3(NN*4/256), dim3(256), 0, stream, x, Wq,bq, Wk,bk, be, We, Aw, qWe, b0);
  hipLaunchKernelGGL(k_hist, dim3(EE/256), dim3(256), 0, stream, ei, deg);
  hipLaunchKernelGGL(k_scan, dim3(1), dim3(1024), 0, stream, deg, rowptr, cursor);
  hipLaunchKernelGGL(k_scatter, dim3(EE/256), dim3(256), 0, stream, ei, ea, cursor, csr_src, csr_attr);
  hipLaunchKernelGGL(k_attn, dim3(NN/4), dim3(256), 0, stream,
                     x, Aw, qWe, b0, rowptr, csr_src, csr_attr,
                     Wv, bv, We, be, Ws, bs, Wb, Wl, bl, hbuf);
  hipLaunchKernelGGL(k_stats1, dim3(NGRAPH), dim3(1024), 0, stream, hbuf, mean);
  hipLaunchKernelGGL(k_stats2, dim3(NGRAPH), dim3(1024), 0, stream, hbuf, mean, gms, gw, scv);
  hipLaunchKernelGGL(k_norm, dim3(NN*32/256), dim3(256), 0, stream, hbuf, mean, scv, gms, gb, Zbuf);
  hipLaunchKernelGGL(k_gemm, dim3(NPER/64, NPER/64, NGRAPH), dim3(256), 0, stream, Zbuf, out);
}